// Round 13
// baseline (929.324 us; speedup 1.0000x reference)
//
#include <hip/hip_runtime.h>
#include <math.h>

#define SEQ 4096
#define CIN 256
#define PROWS 4913   // 17*17*17 padded spatial rows
#define PT 289       // 17*17
#define LROW2 72     // ushorts per conv LDS row (144 B; bank-stride 36 -> 2-way = free)
#define NROWS 170    // 2*5*17 halo rows per 64-pos tile
#define GROW 36      // ushorts per GEMM LDS row

typedef __attribute__((ext_vector_type(8))) short bf16x8;
typedef __attribute__((ext_vector_type(4))) float f32x4;

__device__ __forceinline__ float elu_f(float x) {
    return x > 0.0f ? x : (expf(x) - 1.0f);
}
__device__ __forceinline__ unsigned short f2b(float f) {
    unsigned int u = __float_as_uint(f);
    return (unsigned short)((u + 0x7FFFu + ((u >> 16) & 1u)) >> 16);
}

// ===== zero2: clear both padded activation buffers (halo must be 0) =====
__global__ __launch_bounds__(256) void zero2_kernel(
    uint4* __restrict__ p1, uint4* __restrict__ p2, int n)
{
    int i = blockIdx.x * 256 + threadIdx.x;
    if (i < n) {
        p1[i] = (uint4){0, 0, 0, 0};
        p2[i] = (uint4){0, 0, 0, 0};
    }
}

// ===== prep_t: elubP[b][padded pos][256] = bf16(elu(x)) =====
__global__ __launch_bounds__(256) void prep_t(
    const float* __restrict__ x, unsigned short* __restrict__ elub)
{
    const int b = blockIdx.x >> 5;
    const int s0 = (blockIdx.x & 31) << 7;
    const int cg = blockIdx.y;
    const int tid = threadIdx.x;
    const int s = s0 + (tid & 127);
    const int c0 = cg * 32 + (tid >> 7) * 16;
    const int tt = s >> 8, hh = (s >> 4) & 15, ww = s & 15;
    const size_t prow = (size_t)b * PROWS + (tt + 1) * PT + (hh + 1) * 17 + (ww + 1);
    unsigned short ev[16];
#pragma unroll
    for (int cc = 0; cc < 16; ++cc) {
        float v = x[(((size_t)(b * 256 + c0 + cc)) << 12) + s];
        ev[cc] = f2b(elu_f(v));
    }
    unsigned short* ep = &elub[prow * 256 + c0];
    *(ushort4*)(ep)      = *(ushort4*)&ev[0];
    *(ushort4*)(ep + 4)  = *(ushort4*)&ev[4];
    *(ushort4*)(ep + 8)  = *(ushort4*)&ev[8];
    *(ushort4*)(ep + 12) = *(ushort4*)&ev[12];
}

// ===== wcvt: conv weights -> bf16 in MFMA fragment order =====
__global__ __launch_bounds__(256) void wcvt_kernel(
    const float* __restrict__ w1, const float* __restrict__ w2,
    unsigned short* __restrict__ w1t, unsigned short* __restrict__ w2t)
{
    int idx = blockIdx.x * 256 + threadIdx.x;
    if (idx < 2097152) {
        int layer = idx >> 19;
        int rem = idx & 0x7FFFF;
        int frag = rem >> 9;
        int l = (rem >> 3) & 63;
        int e = rem & 7;
        int ks = frag >> 4, mt = frag & 15;
        int tap = ks >> 3, kc = ks & 7;
        int co = mt * 16 + (l & 15);
        int ci = kc * 32 + (l >> 4) * 8 + e;
        w1t[idx] = f2b(w1[(((size_t)(layer * 256 + co)) * 256 + ci) * 8 + tap]);
    }
    if (idx < 4194304) {
        int layer = idx >> 20;
        int rem = idx & 0xFFFFF;
        int frag = rem >> 9;
        int l = (rem >> 3) & 63;
        int e = rem & 7;
        int ks = frag >> 5, mt = frag & 31;
        int tap = ks >> 3, kc = ks & 7;
        int rp = mt * 16 + (l & 15);
        int grp = rp >> 5, sub = rp & 31;
        int co = (sub < 16) ? (grp * 16 + sub) : (256 + grp * 16 + (sub - 16));
        int ci = kc * 32 + (l >> 4) * 8 + e;
        w2t[idx] = f2b(w2[(((size_t)(layer * 512 + co)) * 256 + ci) * 8 + tap]);
    }
}

// ===== conv1: LDS-staged tap-GEMM, 64-ci chunks (8 barriers). 64co x 64pos =====
__global__ __launch_bounds__(256) void conv1_mfma(
    const unsigned short* __restrict__ inP,
    const unsigned short* __restrict__ wfrag,
    const float* __restrict__ bias,
    unsigned short* __restrict__ outP)
{
    __shared__ unsigned short sX[NROWS * LROW2];   // 23.9 KB

    const int bx = blockIdx.x;
    const int b = bx >> 6, ptile = bx & 63;
    const int t = ptile >> 2, h0 = (ptile & 3) << 2;
    const int mt0 = blockIdx.y << 2;
    const int tid = threadIdx.x;
    const int lane = tid & 63, wv = tid >> 6;
    const int lr = lane & 15, lg = lane >> 4;

    const unsigned short* inB = inP + (size_t)b * PROWS * 256;

    f32x4 acc[4];
#pragma unroll
    for (int mi = 0; mi < 4; ++mi) acc[mi] = (f32x4){0.f, 0.f, 0.f, 0.f};

    for (int kcp = 0; kcp < 4; ++kcp) {
        const int ci0 = kcp << 6;
        __syncthreads();
#pragma unroll
        for (int rnd = 0; rnd < 6; ++rnd) {
            int task = tid + (rnd << 8);
            int row = task >> 3, q = task & 7;
            if (row < NROWS) {
                int dt = row / 85, rem = row - dt * 85;
                int dh = rem / 17, dw = rem - dh * 17;
                int prow = (t + dt) * PT + (h0 + dh) * 17 + dw;
                *(bf16x8*)&sX[row * LROW2 + (q << 3)] =
                    *(const bf16x8*)(inB + (size_t)prow * 256 + ci0 + (q << 3));
            }
        }
        __syncthreads();
#pragma unroll
        for (int tap = 0; tap < 8; ++tap) {
            const int rb = (tap >> 2) * 85 + (wv + ((tap >> 1) & 1)) * 17 + (tap & 1);
#pragma unroll
            for (int g = 0; g < 2; ++g) {
                const int kc = (kcp << 1) + g;
                const unsigned short* wp = wfrag +
                    ((size_t)((((tap << 3) + kc) << 4) + mt0) << 9) + (lane << 3);
                bf16x8 a0 = *(const bf16x8*)(wp);
                bf16x8 a1 = *(const bf16x8*)(wp + 512);
                bf16x8 a2 = *(const bf16x8*)(wp + 1024);
                bf16x8 a3 = *(const bf16x8*)(wp + 1536);
                bf16x8 xb = *(const bf16x8*)&sX[(rb + lr) * LROW2 + (g << 5) + (lg << 3)];
                acc[0] = __builtin_amdgcn_mfma_f32_16x16x32_bf16(a0, xb, acc[0], 0, 0, 0);
                acc[1] = __builtin_amdgcn_mfma_f32_16x16x32_bf16(a1, xb, acc[1], 0, 0, 0);
                acc[2] = __builtin_amdgcn_mfma_f32_16x16x32_bf16(a2, xb, acc[2], 0, 0, 0);
                acc[3] = __builtin_amdgcn_mfma_f32_16x16x32_bf16(a3, xb, acc[3], 0, 0, 0);
            }
        }
    }
    const size_t orow = (size_t)b * PROWS + (t + 1) * PT + (h0 + wv + 1) * 17 + (lr + 1);
#pragma unroll
    for (int mi = 0; mi < 4; ++mi) {
        const int cob = ((mt0 + mi) << 4) + (lg << 2);
        unsigned short v4[4];
#pragma unroll
        for (int r = 0; r < 4; ++r)
            v4[r] = f2b(elu_f(acc[mi][r] + bias[cob + r]));
        *(ushort4*)&outP[orow * 256 + cob] = *(ushort4*)v4;
    }
}

// ===== conv2: LDS-staged tap-GEMM + gate, y-merged (8 mt / block), 64-ci chunks =====
// grid (128, 4): block = 128 W-rows x 64 pos
__global__ __launch_bounds__(256) void conv2_mfma(
    const unsigned short* __restrict__ inP,
    const unsigned short* __restrict__ wfrag,
    const float* __restrict__ bias,
    float* __restrict__ resf,
    unsigned short* __restrict__ elub)
{
    __shared__ unsigned short sX[NROWS * LROW2];

    const int bx = blockIdx.x;
    const int b = bx >> 6, ptile = bx & 63;
    const int t = ptile >> 2, h0 = (ptile & 3) << 2;
    const int mt0 = blockIdx.y << 3;
    const int tid = threadIdx.x;
    const int lane = tid & 63, wv = tid >> 6;
    const int lr = lane & 15, lg = lane >> 4;

    const unsigned short* inB = inP + (size_t)b * PROWS * 256;

    f32x4 acc[8];
#pragma unroll
    for (int mi = 0; mi < 8; ++mi) acc[mi] = (f32x4){0.f, 0.f, 0.f, 0.f};

    for (int kcp = 0; kcp < 4; ++kcp) {
        const int ci0 = kcp << 6;
        __syncthreads();
#pragma unroll
        for (int rnd = 0; rnd < 6; ++rnd) {
            int task = tid + (rnd << 8);
            int row = task >> 3, q = task & 7;
            if (row < NROWS) {
                int dt = row / 85, rem = row - dt * 85;
                int dh = rem / 17, dw = rem - dh * 17;
                int prow = (t + dt) * PT + (h0 + dh) * 17 + dw;
                *(bf16x8*)&sX[row * LROW2 + (q << 3)] =
                    *(const bf16x8*)(inB + (size_t)prow * 256 + ci0 + (q << 3));
            }
        }
        __syncthreads();
#pragma unroll
        for (int tap = 0; tap < 8; ++tap) {
            const int rb = (tap >> 2) * 85 + (wv + ((tap >> 1) & 1)) * 17 + (tap & 1);
#pragma unroll
            for (int g = 0; g < 2; ++g) {
                const int kc = (kcp << 1) + g;
                const unsigned short* wp = wfrag +
                    ((size_t)((((tap << 3) + kc) << 5) + mt0) << 9) + (lane << 3);
                bf16x8 xb = *(const bf16x8*)&sX[(rb + lr) * LROW2 + (g << 5) + (lg << 3)];
#pragma unroll
                for (int mi = 0; mi < 8; ++mi) {
                    bf16x8 am = *(const bf16x8*)(wp + (mi << 9));
                    acc[mi] = __builtin_amdgcn_mfma_f32_16x16x32_bf16(am, xb, acc[mi], 0, 0, 0);
                }
            }
        }
    }
    const int s = (t << 8) + ((h0 + wv) << 4) + lr;
    const size_t prow = (size_t)b * PROWS + (t + 1) * PT + (h0 + wv + 1) * 17 + (lr + 1);
#pragma unroll
    for (int p = 0; p < 4; ++p) {
        const int chb = (((mt0 >> 1) + p) << 4) + (lg << 2);
        unsigned short e4[4];
#pragma unroll
        for (int r = 0; r < 4; ++r) {
            const int ch = chb + r;
            float av = acc[2 * p][r] + bias[ch];
            float gv = acc[2 * p + 1][r] + bias[ch + 256];
            float add = av / (1.0f + expf(-gv));
            size_t ridx = (((size_t)(b * 256 + ch)) << 12) + s;
            float rn = resf[ridx] + add;
            resf[ridx] = rn;
            e4[r] = f2b(elu_f(rn));
        }
        *(ushort4*)&elub[prow * 256 + chb] = *(ushort4*)e4;
    }
}

// ===== pack: xq[b][s][320] = bf16(res | orig | pos | 0) =====
__global__ __launch_bounds__(256) void pack_kernel(
    const float* __restrict__ res, const float* __restrict__ orig,
    unsigned short* __restrict__ xq)
{
    const int b = blockIdx.x >> 5;
    const int s0 = (blockIdx.x & 31) << 7;
    const int cg = blockIdx.y;
    const int tid = threadIdx.x;
    const int s = s0 + (tid & 127);
    const int c0 = cg * 32 + (tid >> 7) * 16;

    unsigned short xv[16];
    if (cg < 8) {
#pragma unroll
        for (int cc = 0; cc < 16; ++cc) {
            int c = c0 + cc;
            float v = res[(size_t)((b * 256 + c) << 12) + s];
            xv[cc] = f2b(v);
        }
    } else if (cg == 8) {
#pragma unroll
        for (int cc = 0; cc < 16; ++cc) {
            int c = c0 + cc;
            float v;
            if (c < 259)      v = orig[(size_t)((b * 3 + (c - 256)) << 12) + s];
            else if (c == 259) v = -0.5f + (float)(s >> 8) * 0.0625f;
            else if (c == 260) v = -0.5f + (float)((s >> 4) & 15) * 0.0625f;
            else if (c == 261) v = -0.5f + (float)(s & 15) * 0.0625f;
            else               v = 0.0f;
            xv[cc] = f2b(v);
        }
    } else {
#pragma unroll
        for (int cc = 0; cc < 16; ++cc) xv[cc] = 0;
    }
    unsigned short* xp = &xq[((size_t)(b << 12) + s) * 320 + c0];
    *(ushort4*)(xp)      = *(ushort4*)&xv[0];
    *(ushort4*)(xp + 4)  = *(ushort4*)&xv[4];
    *(ushort4*)(xp + 8)  = *(ushort4*)&xv[8];
    *(ushort4*)(xp + 12) = *(ushort4*)&xv[12];
}

// ===== wcvt2: all linear weights -> bf16 in MFMA fragment order =====
__global__ __launch_bounds__(256) void wcvt2_kernel(
    const float* __restrict__ qw, const float* __restrict__ kw,
    const float* __restrict__ vw, const float* __restrict__ aw,
    const float* __restrict__ rw, const float* __restrict__ ow,
    unsigned short* __restrict__ wqkv, unsigned short* __restrict__ awb,
    unsigned short* __restrict__ rwb, unsigned short* __restrict__ owb)
{
    int idx = blockIdx.x * 256 + threadIdx.x;
    if (idx < 61440) {
        int frag = idx >> 9, l = (idx >> 3) & 63, e = idx & 7;
        int kc = frag / 12, mt = frag - kc * 12;
        int r = mt * 16 + (l & 15);
        int c = kc * 32 + ((l >> 4) << 3) + e;
        float v = 0.0f;
        if (c < 262) {
            if (r < 16)       v = qw[r * 262 + c];
            else if (r < 32)  v = kw[(r - 16) * 262 + c];
            else if (r < 160) v = vw[(r - 32) * 262 + c];
        }
        wqkv[idx] = f2b(v);
    } else if (idx < 94208) {
        int j = idx - 61440;
        int frag = j >> 9, l = (j >> 3) & 63, e = j & 7;
        int kc = frag >> 4, mt = frag & 15;
        int r = mt * 16 + (l & 15);
        int c = kc * 32 + ((l >> 4) << 3) + e;
        awb[j] = f2b(aw[r * 128 + c]);
    } else if (idx < 159744) {
        int j = idx - 94208;
        int frag = j >> 9, l = (j >> 3) & 63, e = j & 7;
        int kc = frag >> 4, mt = frag & 15;
        int r = mt * 16 + (l & 15);
        int c = kc * 32 + ((l >> 4) << 3) + e;
        rwb[j] = f2b(rw[r * 256 + c]);
    } else if (idx < 225280) {
        int j = idx - 159744;
        int frag = j >> 9, l = (j >> 3) & 63, e = j & 7;
        int kc = frag >> 4, mt = frag & 15;
        int r = mt * 16 + (l & 15);
        int c = kc * 32 + ((l >> 4) << 3) + e;
        owb[j] = f2b(ow[r * 256 + c]);
    }
}

// ===== qkv GEMM (LDS-staged X, fragment W) =====
__global__ __launch_bounds__(256) void qkv_gemm(
    const unsigned short* __restrict__ Wf, const unsigned short* __restrict__ Xt,
    const float* __restrict__ qb, const float* __restrict__ kb,
    const float* __restrict__ vb,
    unsigned short* __restrict__ qbt, unsigned short* __restrict__ kbt,
    unsigned short* __restrict__ vbt)
{
    __shared__ unsigned short sX[128 * GROW];

    const int b = blockIdx.x >> 5;
    const int s0 = (blockIdx.x & 31) << 7;
    const int mt0 = blockIdx.y << 2;
    const int tid = threadIdx.x;
    const int lane = tid & 63, wv = tid >> 6;
    const int lr = lane & 15, lg = lane >> 4;

    f32x4 acc[4][2];
#pragma unroll
    for (int mi = 0; mi < 4; ++mi)
#pragma unroll
        for (int ni = 0; ni < 2; ++ni) acc[mi][ni] = (f32x4){0.f, 0.f, 0.f, 0.f};

    for (int kc = 0; kc < 10; ++kc) {
        __syncthreads();
#pragma unroll
        for (int rnd = 0; rnd < 2; ++rnd) {
            int task = tid + (rnd << 8);
            int row = task >> 2, q = task & 3;
            *(bf16x8*)&sX[row * GROW + (q << 3)] =
                *(const bf16x8*)(Xt + ((size_t)(b << 12) + s0 + row) * 320
                                 + kc * 32 + (q << 3));
        }
        __syncthreads();
        const unsigned short* wp = Wf + ((size_t)(kc * 12 + mt0) << 9) + (lane << 3);
        bf16x8 a0 = *(const bf16x8*)(wp);
        bf16x8 a1 = *(const bf16x8*)(wp + 512);
        bf16x8 a2 = *(const bf16x8*)(wp + 1024);
        bf16x8 a3 = *(const bf16x8*)(wp + 1536);
        bf16x8 x0 = *(const bf16x8*)&sX[(wv * 32 + lr) * GROW + (lg << 3)];
        bf16x8 x1 = *(const bf16x8*)&sX[(wv * 32 + 16 + lr) * GROW + (lg << 3)];
        acc[0][0] = __builtin_amdgcn_mfma_f32_16x16x32_bf16(a0, x0, acc[0][0], 0, 0, 0);
        acc[0][1] = __builtin_amdgcn_mfma_f32_16x16x32_bf16(a0, x1, acc[0][1], 0, 0, 0);
        acc[1][0] = __builtin_amdgcn_mfma_f32_16x16x32_bf16(a1, x0, acc[1][0], 0, 0, 0);
        acc[1][1] = __builtin_amdgcn_mfma_f32_16x16x32_bf16(a1, x1, acc[1][1], 0, 0, 0);
        acc[2][0] = __builtin_amdgcn_mfma_f32_16x16x32_bf16(a2, x0, acc[2][0], 0, 0, 0);
        acc[2][1] = __builtin_amdgcn_mfma_f32_16x16x32_bf16(a2, x1, acc[2][1], 0, 0, 0);
        acc[3][0] = __builtin_amdgcn_mfma_f32_16x16x32_bf16(a3, x0, acc[3][0], 0, 0, 0);
        acc[3][1] = __builtin_amdgcn_mfma_f32_16x16x32_bf16(a3, x1, acc[3][1], 0, 0, 0);
    }
    const int co0 = mt0 << 4;
#pragma unroll
    for (int mi = 0; mi < 4; ++mi)
#pragma unroll
    for (int ni = 0; ni < 2; ++ni)
#pragma unroll
    for (int r = 0; r < 4; ++r) {
        int co = co0 + mi * 16 + lg * 4 + r;
        if (co >= 160) continue;
        int s = s0 + wv * 32 + ni * 16 + lr;
        float bias = (co < 16) ? qb[co] : ((co < 32) ? kb[co - 16] : vb[co - 32]);
        float v = acc[mi][ni][r] + bias;
        if (co < 16)      qbt[((size_t)(b << 12) + s) * 16 + co] = f2b(v);
        else if (co < 32) kbt[((size_t)(b << 12) + s) * 16 + (co - 16)] = f2b(v);
        else              vbt[((size_t)((b << 7) + (co - 32)) << 12) + s] = f2b(v);
    }
}

// ===== attention partial (round-10 form) =====
__global__ __launch_bounds__(256) void attn_part2(
    const unsigned short* __restrict__ qbt, const unsigned short* __restrict__ kbt,
    const unsigned short* __restrict__ vbt,
    float* __restrict__ pacc, float* __restrict__ pml)
{
    const int bx = blockIdx.x;
    const int b = bx >> 8;
    const int qt = (bx >> 2) & 63;
    const int seg = bx & 3;
    const int q0 = qt << 6;
    const int nch = (qt >> 1) + 1;
    const int c_lo = seg << 3;
    if (c_lo >= nch) return;
    const int c_hi = min(c_lo + 8, nch);

    __shared__ unsigned short sK[128 * 16];
    __shared__ unsigned short sP[4][16 * 136];

    const int tid = threadIdx.x;
    const int lane = tid & 63, wv = tid >> 6;
    const int lr = lane & 15, lg = lane >> 4;
    const int qa = q0 + wv * 16 + lr;
    const float scale = 1.0f / sqrtf(259.0f);

    bf16x8 qf = (bf16x8){0, 0, 0, 0, 0, 0, 0, 0};
    if (lg < 2)
        qf = *(const bf16x8*)(qbt + ((size_t)(b << 12) + qa) * 16 + lg * 8);

    f32x4 oacc[8];
#pragma unroll
    for (int vct = 0; vct < 8; ++vct) oacc[vct] = (f32x4){0.f, 0.f, 0.f, 0.f};
    float m = -1e30f, l = 0.0f;

    unsigned short* myP = &sP[wv][0];

    for (int kc = c_lo; kc < c_hi; ++kc) {
        const int kv0 = kc << 7;
        __syncthreads();
        *(bf16x8*)&sK[(tid >> 1) * 16 + (tid & 1) * 8] =
            *(const bf16x8*)(kbt + ((size_t)(b << 12) + kv0 + (tid >> 1)) * 16 + (tid & 1) * 8);
        __syncthreads();

        f32x4 sc[8];
#pragma unroll
        for (int kvt = 0; kvt < 8; ++kvt) {
            bf16x8 af = (bf16x8){0, 0, 0, 0, 0, 0, 0, 0};
            if (lg < 2)
                af = *(const bf16x8*)&sK[(kvt * 16 + lr) * 16 + lg * 8];
            sc[kvt] = __builtin_amdgcn_mfma_f32_16x16x32_bf16(
                af, qf, (f32x4){0.f, 0.f, 0.f, 0.f}, 0, 0, 0);
        }
        float mc = -1e30f;
#pragma unroll
        for (int kvt = 0; kvt < 8; ++kvt) {
#pragma unroll
            for (int r = 0; r < 4; ++r) {
                int kv = kv0 + kvt * 16 + lg * 4 + r;
                float s = (kv < qa) ? sc[kvt][r] * scale : -1e30f;
                sc[kvt][r] = s;
                mc = fmaxf(mc, s);
            }
        }
        mc = fmaxf(mc, __shfl_xor(mc, 16, 64));
        mc = fmaxf(mc, __shfl_xor(mc, 32, 64));
        float mn = fmaxf(m, mc);
        float fac = __expf(m - mn);
        float ls = 0.0f;
#pragma unroll
        for (int kvt = 0; kvt < 8; ++kvt) {
#pragma unroll
            for (int e = 0; e < 2; ++e) {
                float s0v = sc[kvt][2 * e];
                float s1v = sc[kvt][2 * e + 1];
                float p0 = (s0v <= -1e29f) ? 0.f : __expf(s0v - mn);
                float p1 = (s1v <= -1e29f) ? 0.f : __expf(s1v - mn);
                ls += p0 + p1;
                unsigned int pk = (unsigned int)f2b(p0) | ((unsigned int)f2b(p1) << 16);
                int kv = kvt * 16 + lg * 4 + 2 * e;
                *(unsigned int*)&myP[lr * 136 + kv] = pk;
            }
        }
        ls += __shfl_xor(ls, 16, 64);
        ls += __shfl_xor(ls, 32, 64);
        l = l * fac + ls;
        m = mn;
#pragma unroll
        for (int vct = 0; vct < 8; ++vct) {
            oacc[vct][0] *= fac; oacc[vct][1] *= fac;
            oacc[vct][2] *= fac; oacc[vct][3] *= fac;
        }
#pragma unroll
        for (int ks = 0; ks < 4; ++ks) {
            bf16x8 pf = *(const bf16x8*)&myP[lr * 136 + ks * 32 + lg * 8];
#pragma unroll
            for (int vct = 0; vct < 8; ++vct) {
                bf16x8 vf = *(const bf16x8*)(vbt +
                    ((size_t)((b << 7) + vct * 16 + lr) << 12) + kv0 + ks * 32 + lg * 8);
                oacc[vct] = __builtin_amdgcn_mfma_f32_16x16x32_bf16(
                    vf, pf, oacc[vct], 0, 0, 0);
            }
        }
    }

    const int a_ = qt >> 4;
    const int slot = b * 160 + 8 * a_ * (a_ + 1) + (qt & 15) * (a_ + 1) + seg;
    float* ap = pacc + (size_t)slot * 8192;
#pragma unroll
    for (int vct = 0; vct < 8; ++vct)
        *(f32x4*)&ap[(wv * 16 + lr) * 128 + vct * 16 + lg * 4] = oacc[vct];
    if (lg == 0) {
        pml[slot * 128 + (wv * 16 + lr) * 2]     = m;
        pml[slot * 128 + (wv * 16 + lr) * 2 + 1] = l;
    }
}

// ===== attention combine =====
__global__ __launch_bounds__(256) void attn_combine2(
    const float* __restrict__ pacc, const float* __restrict__ pml,
    unsigned short* __restrict__ attEb)
{
    const int bx = blockIdx.x;
    const int b = bx >> 7;
    const int qt = (bx >> 1) & 63;
    const int half = bx & 1;
    const int a_ = qt >> 4;
    const int nseg_alloc = a_ + 1;
    const int nch = (qt >> 1) + 1;
    const int nseg = (nch + 7) >> 3;
    const int base = b * 160 + 8 * a_ * (a_ + 1) + (qt & 15) * nseg_alloc;
    const int tid = threadIdx.x;
    const int qq = (tid >> 3) + half * 32;
    const int vg = tid & 7;

    float mi_[4], li_[4];
    float m = -1e30f;
    for (int i = 0; i < nseg; ++i) {
        mi_[i] = pml[(base + i) * 128 + qq * 2];
        li_[i] = pml[(base + i) * 128 + qq * 2 + 1];
        m = fmaxf(m, mi_[i]);
    }
    float w[4];
    float l = 0.f;
    for (int i = 0; i < nseg; ++i) {
        float wi = (mi_[i] <= -1e29f) ? 0.f : __expf(mi_[i] - m);
        w[i] = wi;
        l += wi * li_[i];
    }
    float inv = (l > 0.f) ? 1.f / l : 0.f;
    int q = (qt << 6) + qq;
#pragma unroll
    for (int v4 = 0; v4 < 4; ++v4) {
        int vc = vg * 16 + v4 * 4;
        float o0 = 0.f, o1 = 0.f, o2 = 0.f, o3 = 0.f;
        for (int i = 0; i < nseg; ++i) {
            f32x4 a = *(const f32x4*)(pacc + (size_t)(base + i) * 8192 + qq * 128 + vc);
            o0 = fmaf(w[i], a[0], o0);
            o1 = fmaf(w[i], a[1], o1);
            o2 = fmaf(w[i], a[2], o2);
            o3 = fmaf(w[i], a[3], o3);
        }
        unsigned short r0 = f2b(elu_f(o0 * inv));
        unsigned short r1 = f2b(elu_f(o1 * inv));
        unsigned short r2 = f2b(elu_f(o2 * inv));
        unsigned short r3 = f2b(elu_f(o3 * inv));
        ushort4 pk = {r0, r1, r2, r3};
        *(ushort4*)&attEb[((size_t)(b << 12) + q) * 128 + vc] = pk;
    }
}

// ===== final_ab GEMM (LDS-staged) =====
__global__ __launch_bounds__(256) void final_ab_gemm(
    const unsigned short* __restrict__ W1f, const unsigned short* __restrict__ W2f,
    const unsigned short* __restrict__ X1, const unsigned short* __restrict__ X2,
    const float* __restrict__ b1, const float* __restrict__ b2,
    unsigned short* __restrict__ sum2b)
{
    __shared__ unsigned short sX[128 * GROW];

    const int b = blockIdx.x >> 5;
    const int s0 = (blockIdx.x & 31) << 7;
    const int mt0 = blockIdx.y << 2;
    const int tid = threadIdx.x;
    const int lane = tid & 63, wv = tid >> 6;
    const int lr = lane & 15, lg = lane >> 4;

    f32x4 acc1[4][2], acc2[4][2];
#pragma unroll
    for (int mi = 0; mi < 4; ++mi)
#pragma unroll
        for (int ni = 0; ni < 2; ++ni) {
            acc1[mi][ni] = (f32x4){0.f, 0.f, 0.f, 0.f};
            acc2[mi][ni] = (f32x4){0.f, 0.f, 0.f, 0.f};
        }

    for (int kc = 0; kc < 4; ++kc) {
        __syncthreads();
#pragma unroll
        for (int rnd = 0; rnd < 2; ++rnd) {
            int task = tid + (rnd << 8);
            int row = task >> 2, q = task & 3;
            *(bf16x8*)&sX[row * GROW + (q << 3)] =
                *(const bf16x8*)(X1 + ((size_t)(b << 12) + s0 + row) * 128
                                 + kc * 32 + (q << 3));
        }
        __syncthreads();
        const unsigned short* wp = W1f + ((size_t)((kc << 4) + mt0) << 9) + (lane << 3);
        bf16x8 a0 = *(const bf16x8*)(wp);
        bf16x8 a1 = *(const bf16x8*)(wp + 512);
        bf16x8 a2 = *(const bf16x8*)(wp + 1024);
        bf16x8 a3 = *(const bf16x8*)(wp + 1536);
        bf16x8 x0 = *(const bf16x8*)&sX[(wv * 32 + lr) * GROW + (lg << 3)];
        bf16x8 x1 = *(const bf16x8*)&sX[(wv * 32 + 16 + lr) * GROW + (lg << 3)];
        acc1[0][0] = __builtin_amdgcn_mfma_f32_16x16x32_bf16(a0, x0, acc1[0][0], 0, 0, 0);
        acc1[0][1] = __builtin_amdgcn_mfma_f32_16x16x32_bf16(a0, x1, acc1[0][1], 0, 0, 0);
        acc1[1][0] = __builtin_amdgcn_mfma_f32_16x16x32_bf16(a1, x0, acc1[1][0], 0, 0, 0);
        acc1[1][1] = __builtin_amdgcn_mfma_f32_16x16x32_bf16(a1, x1, acc1[1][1], 0, 0, 0);
        acc1[2][0] = __builtin_amdgcn_mfma_f32_16x16x32_bf16(a2, x0, acc1[2][0], 0, 0, 0);
        acc1[2][1] = __builtin_amdgcn_mfma_f32_16x16x32_bf16(a2, x1, acc1[2][1], 0, 0, 0);
        acc1[3][0] = __builtin_amdgcn_mfma_f32_16x16x32_bf16(a3, x0, acc1[3][0], 0, 0, 0);
        acc1[3][1] = __builtin_amdgcn_mfma_f32_16x16x32_bf16(a3, x1, acc1[3][1], 0, 0, 0);
    }
    for (int kc = 0; kc < 8; ++kc) {
        __syncthreads();
#pragma unroll
        for (int rnd = 0; rnd < 2; ++rnd) {
            int task = tid + (rnd << 8);
            int row = task >> 2, q = task & 3;
            int s = s0 + row;
            int tt = s >> 8, hh = (s >> 4) & 15, ww = s & 15;
            size_t prow = (size_t)b * PROWS + (tt + 1) * PT + (hh + 1) * 17 + (ww + 1);
            *(bf16x8*)&sX[row * GROW + (q << 3)] =
                *(const bf16x8*)(X2 + prow * 256 + kc * 32 + (q << 3));
        }
        __syncthreads();
        const unsigned short* wp = W2f + ((size_t)((kc << 4) + mt0) << 9) + (lane << 3);
        bf16x8 a0 = *(const bf16x8*)(wp);
        bf16x8 a1 = *(const bf16x8*)(wp + 512);
        bf16x8 a2 = *(const bf16x8*)(wp + 1024);
        bf16x8 a3 = *(const bf16x8*)(wp + 1536);
        bf16x8 x0 = *(const bf16x8*)&sX[(wv * 32 + lr) * GROW + (lg << 3)];
        bf16x8 x1 = *(const bf16x8*)&sX[(wv * 32 + 16 + lr) * GROW + (lg << 3)];
        acc2[0][0] = __builtin_amdgcn_mfma_f32_16x16x32_bf16(a0, x0, acc2[0][0], 0, 0, 0);
        acc2[0][1] = __builtin_amdgcn_mfma_f32_16x16x32_bf16(a0, x1, acc2[0][1], 0, 0, 0);
        acc2[1][0] = __builtin_amdgcn_mfma_f32_16x16x32_bf16(a1, x0, acc2[1][0], 0, 0, 0);
        acc2[1][1] = __builtin_amdgcn_mfma_f32_16x16x32_bf16(a1, x1, acc2[1][1], 0, 0, 0);
        acc2[2][0] = __builtin_amdgcn_mfma_f32_16x16x32_bf16(a2, x0, acc2[2][0], 0, 0, 0);
        acc2[2][1] = __builtin_amdgcn_mfma_f32_16x16x32_bf16(a2, x1, acc2[2][1], 0, 0, 0);
        acc2[3][0] = __builtin_amdgcn_mfma_f32_16x16x32_bf16(a3, x0, acc2[3][0], 0, 0, 0);
        acc2[3][1] = __builtin_amdgcn_mfma_f32_16x16x32_bf16(a3, x1, acc2[3][1], 0, 0, 0);
    }
    const int co0 = mt0 << 4;
#pragma unroll
    for (int mi = 0; mi < 4; ++mi)
#pragma unroll
    for (int ni = 0; ni < 2; ++ni)
#pragma unroll
    for (int r = 0; r < 4; ++r) {
        int co = co0 + mi * 16 + lg * 4 + r;
        int s = s0 + wv * 32 + ni * 16 + lr;
        float v1 = elu_f(acc1[mi][ni][r] + b1[co]);
        float v2 = elu_f(acc2[mi][ni][r] + b2[co]);
        sum2b[((size_t)(b << 12) + s) * 256 + co] = f2b(elu_f(v1 + v2));
    }
}

// ===== final_c GEMM (LDS-staged) =====
__global__ __launch_bounds__(256) void final_c_gemm(
    const unsigned short* __restrict__ Wf, const unsigned short* __restrict__ Xt,
    const float* __restrict__ bias, float* __restrict__ out)
{
    __shared__ unsigned short sX[128 * GROW];

    const int b = blockIdx.x >> 5;
    const int s0 = (blockIdx.x & 31) << 7;
    const int mt0 = blockIdx.y << 2;
    const int tid = threadIdx.x;
    const int lane = tid & 63, wv = tid >> 6;
    const int lr = lane & 15, lg = lane >> 4;

    f32x4 acc[4][2];
#pragma unroll
    for (int mi = 0; mi < 4; ++mi)
#pragma unroll
        for (int ni = 0; ni < 2; ++ni) acc[mi][ni] = (f32x4){0.f, 0.f, 0.f, 0.f};

    for (int kc = 0; kc < 8; ++kc) {
        __syncthreads();
#pragma unroll
        for (int rnd = 0; rnd < 2; ++rnd) {
            int task = tid + (rnd << 8);
            int row = task >> 2, q = task & 3;
            *(bf16x8*)&sX[row * GROW + (q << 3)] =
                *(const bf16x8*)(Xt + ((size_t)(b << 12) + s0 + row) * 256
                                 + kc * 32 + (q << 3));
        }
        __syncthreads();
        const unsigned short* wp = Wf + ((size_t)((kc << 4) + mt0) << 9) + (lane << 3);
        bf16x8 a0 = *(const bf16x8*)(wp);
        bf16x8 a1 = *(const bf16x8*)(wp + 512);
        bf16x8 a2 = *(const bf16x8*)(wp + 1024);
        bf16x8 a3 = *(const bf16x8*)(wp + 1536);
        bf16x8 x0 = *(const bf16x8*)&sX[(wv * 32 + lr) * GROW + (lg << 3)];
        bf16x8 x1 = *(const bf16x8*)&sX[(wv * 32 + 16 + lr) * GROW + (lg << 3)];
        acc[0][0] = __builtin_amdgcn_mfma_f32_16x16x32_bf16(a0, x0, acc[0][0], 0, 0, 0);
        acc[0][1] = __builtin_amdgcn_mfma_f32_16x16x32_bf16(a0, x1, acc[0][1], 0, 0, 0);
        acc[1][0] = __builtin_amdgcn_mfma_f32_16x16x32_bf16(a1, x0, acc[1][0], 0, 0, 0);
        acc[1][1] = __builtin_amdgcn_mfma_f32_16x16x32_bf16(a1, x1, acc[1][1], 0, 0, 0);
        acc[2][0] = __builtin_amdgcn_mfma_f32_16x16x32_bf16(a2, x0, acc[2][0], 0, 0, 0);
        acc[2][1] = __builtin_amdgcn_mfma_f32_16x16x32_bf16(a2, x1, acc[2][1], 0, 0, 0);
        acc[3][0] = __builtin_amdgcn_mfma_f32_16x16x32_bf16(a3, x0, acc[3][0], 0, 0, 0);
        acc[3][1] = __builtin_amdgcn_mfma_f32_16x16x32_bf16(a3, x1, acc[3][1], 0, 0, 0);
    }
    const int co0 = mt0 << 4;
#pragma unroll
    for (int mi = 0; mi < 4; ++mi)
#pragma unroll
    for (int ni = 0; ni < 2; ++ni)
#pragma unroll
    for (int r = 0; r < 4; ++r) {
        int co = co0 + mi * 16 + lg * 4 + r;
        int s = s0 + wv * 32 + ni * 16 + lr;
        out[((size_t)(b * 256 + co) << 12) + s] = elu_f(acc[mi][ni][r] + bias[co]);
    }
}

extern "C" void kernel_launch(void* const* d_in, const int* in_sizes, int n_in,
                              void* d_out, int out_size, void* d_ws, size_t ws_size,
                              hipStream_t stream) {
    const float* x      = (const float*)d_in[0];
    const float* orig   = (const float*)d_in[1];
    const float* rb_w1  = (const float*)d_in[2];
    const float* rb_b1  = (const float*)d_in[3];
    const float* rb_w2  = (const float*)d_in[4];
    const float* rb_b2  = (const float*)d_in[5];
    const float* q_w    = (const float*)d_in[6];
    const float* q_b    = (const float*)d_in[7];
    const float* k_w    = (const float*)d_in[8];
    const float* k_b    = (const float*)d_in[9];
    const float* v_w    = (const float*)d_in[10];
    const float* v_b    = (const float*)d_in[11];
    const float* attn_w = (const float*)d_in[12];
    const float* attn_b = (const float*)d_in[13];
    const float* resc_w = (const float*)d_in[14];
    const float* resc_b = (const float*)d_in[15];
    const float* out_w  = (const float*)d_in[16];
    const float* out_b  = (const float*)d_in[17];
    float* out = (float*)d_out;

    char* base = (char*)d_ws;
    float*          res   = (float*)(base);                          // 0..8MB
    unsigned short* elubP = (unsigned short*)(base + (8u << 20));    // 8..13MB padded
    unsigned short* o1P   = (unsigned short*)(base + (13u << 20));   // 13..18MB padded
    unsigned short* w1t   = (unsigned short*)(base + (18u << 20));   // 18..22MB
    unsigned short* w2t   = (unsigned short*)(base + (22u << 20));   // 22..30MB
    unsigned short* vbt   = o1P;                                     // 2MB @13MB
    unsigned short* attEb = (unsigned short*)(base + (15u << 20));   // 2MB @15MB
    unsigned short* sum2b = w1t;
    unsigned short* xqkvB = w2t;                                     // 5MB @22MB
    float*          pacc  = (float*)(base + (22u << 20));            // 10MB @22MB
    unsigned short* qbt   = (unsigned short*)(base + (32u << 20));
    unsigned short* kbt   = (unsigned short*)(base + (32u << 20) + 262144);
    unsigned short* wqkvB = (unsigned short*)(base + (32u << 20) + 524288);
    unsigned short* attnWb= (unsigned short*)(base + (32u << 20) + 655360);
    unsigned short* rescWb= (unsigned short*)(base + (32u << 20) + 720896);
    unsigned short* outWb = (unsigned short*)(base + (32u << 20) + 851968);
    float*          pml   = (float*)(base + (32u << 20) + 983040);

    const int nz = (2 * PROWS * 256 * 2) / 16;
    zero2_kernel<<<(nz + 255) / 256, 256, 0, stream>>>(
        (uint4*)elubP, (uint4*)o1P, nz);

    hipMemcpyAsync(res, x, (size_t)2097152 * sizeof(float),
                   hipMemcpyDeviceToDevice, stream);
    prep_t<<<dim3(64, 8), 256, 0, stream>>>(x, elubP);
    wcvt_kernel<<<16384, 256, 0, stream>>>(rb_w1, rb_w2, w1t, w2t);

    for (int i = 0; i < 4; ++i) {
        conv1_mfma<<<dim3(128, 4), 256, 0, stream>>>(
            elubP, w1t + (size_t)i * 524288, rb_b1 + i * 256, o1P);
        conv2_mfma<<<dim3(128, 4), 256, 0, stream>>>(
            o1P, w2t + (size_t)i * 1048576, rb_b2 + i * 512, res, elubP);
    }

    pack_kernel<<<dim3(64, 10), 256, 0, stream>>>(res, orig, xqkvB);
    wcvt2_kernel<<<880, 256, 0, stream>>>(q_w, k_w, v_w, attn_w, resc_w, out_w,
                                          wqkvB, attnWb, rescWb, outWb);

    qkv_gemm<<<dim3(64, 3), 256, 0, stream>>>(wqkvB, xqkvB, q_b, k_b, v_b,
                                              qbt, kbt, vbt);

    attn_part2<<<512, 256, 0, stream>>>(qbt, kbt, vbt, pacc, pml);
    attn_combine2<<<256, 256, 0, stream>>>(pacc, pml, attEb);

    final_ab_gemm<<<dim3(64, 4), 256, 0, stream>>>(
        attnWb, rescWb, attEb, elubP, attn_b, resc_b, sum2b);

    final_c_gemm<<<dim3(64, 4), 256, 0, stream>>>(outWb, sum2b, out_b, out);
}

// Round 14
// 420.593 us; speedup vs baseline: 2.2096x; 2.2096x over previous
//
#include <hip/hip_runtime.h>
#include <math.h>

#define SEQ 4096
#define CIN 256
#define PROWS 4913   // 17*17*17 padded spatial rows
#define PT 289       // 17*17
#define LROW 40      // ushorts per conv LDS row (80 B)
#define NROWS 170    // 2*5*17 halo rows per 64-pos tile
#define GROW 36      // ushorts per GEMM LDS row (72 B, bank-stride 18 = conflict-free)

typedef __attribute__((ext_vector_type(8))) short bf16x8;
typedef __attribute__((ext_vector_type(4))) float f32x4;

__device__ __forceinline__ float elu_f(float x) {
    return x > 0.0f ? x : (expf(x) - 1.0f);
}
__device__ __forceinline__ unsigned short f2b(float f) {
    unsigned int u = __float_as_uint(f);
    return (unsigned short)((u + 0x7FFFu + ((u >> 16) & 1u)) >> 16);
}

// ===== zero2: clear both padded activation buffers (halo must be 0) =====
__global__ __launch_bounds__(256) void zero2_kernel(
    uint4* __restrict__ p1, uint4* __restrict__ p2, int n)
{
    int i = blockIdx.x * 256 + threadIdx.x;
    if (i < n) {
        p1[i] = (uint4){0, 0, 0, 0};
        p2[i] = (uint4){0, 0, 0, 0};
    }
}

// ===== prep_t: elubP[b][padded pos][256] = bf16(elu(x)) =====
__global__ __launch_bounds__(256) void prep_t(
    const float* __restrict__ x, unsigned short* __restrict__ elub)
{
    const int b = blockIdx.x >> 5;
    const int s0 = (blockIdx.x & 31) << 7;
    const int cg = blockIdx.y;
    const int tid = threadIdx.x;
    const int s = s0 + (tid & 127);
    const int c0 = cg * 32 + (tid >> 7) * 16;
    const int tt = s >> 8, hh = (s >> 4) & 15, ww = s & 15;
    const size_t prow = (size_t)b * PROWS + (tt + 1) * PT + (hh + 1) * 17 + (ww + 1);
    unsigned short ev[16];
#pragma unroll
    for (int cc = 0; cc < 16; ++cc) {
        float v = x[(((size_t)(b * 256 + c0 + cc)) << 12) + s];
        ev[cc] = f2b(elu_f(v));
    }
    unsigned short* ep = &elub[prow * 256 + c0];
    *(ushort4*)(ep)      = *(ushort4*)&ev[0];
    *(ushort4*)(ep + 4)  = *(ushort4*)&ev[4];
    *(ushort4*)(ep + 8)  = *(ushort4*)&ev[8];
    *(ushort4*)(ep + 12) = *(ushort4*)&ev[12];
}

// ===== wcvt: conv weights -> bf16 in MFMA fragment order =====
__global__ __launch_bounds__(256) void wcvt_kernel(
    const float* __restrict__ w1, const float* __restrict__ w2,
    unsigned short* __restrict__ w1t, unsigned short* __restrict__ w2t)
{
    int idx = blockIdx.x * 256 + threadIdx.x;
    if (idx < 2097152) {
        int layer = idx >> 19;
        int rem = idx & 0x7FFFF;
        int frag = rem >> 9;
        int l = (rem >> 3) & 63;
        int e = rem & 7;
        int ks = frag >> 4, mt = frag & 15;
        int tap = ks >> 3, kc = ks & 7;
        int co = mt * 16 + (l & 15);
        int ci = kc * 32 + (l >> 4) * 8 + e;
        w1t[idx] = f2b(w1[(((size_t)(layer * 256 + co)) * 256 + ci) * 8 + tap]);
    }
    if (idx < 4194304) {
        int layer = idx >> 20;
        int rem = idx & 0xFFFFF;
        int frag = rem >> 9;
        int l = (rem >> 3) & 63;
        int e = rem & 7;
        int ks = frag >> 5, mt = frag & 31;
        int tap = ks >> 3, kc = ks & 7;
        int rp = mt * 16 + (l & 15);
        int grp = rp >> 5, sub = rp & 31;
        int co = (sub < 16) ? (grp * 16 + sub) : (256 + grp * 16 + (sub - 16));
        int ci = kc * 32 + (l >> 4) * 8 + e;
        w2t[idx] = f2b(w2[(((size_t)(layer * 512 + co)) * 256 + ci) * 8 + tap]);
    }
}

// ===== conv1: LDS-staged tap-GEMM. block 256thr = 64co x 64pos =====
__global__ __launch_bounds__(256) void conv1_mfma(
    const unsigned short* __restrict__ inP,
    const unsigned short* __restrict__ wfrag,
    const float* __restrict__ bias,
    unsigned short* __restrict__ outP)
{
    __shared__ unsigned short sX[NROWS * LROW];

    const int bx = blockIdx.x;
    const int b = bx >> 6, ptile = bx & 63;
    const int t = ptile >> 2, h0 = (ptile & 3) << 2;
    const int mt0 = blockIdx.y << 2;
    const int tid = threadIdx.x;
    const int lane = tid & 63, wv = tid >> 6;
    const int lr = lane & 15, lg = lane >> 4;

    const unsigned short* inB = inP + (size_t)b * PROWS * 256;

    f32x4 acc[4];
#pragma unroll
    for (int mi = 0; mi < 4; ++mi) acc[mi] = (f32x4){0.f, 0.f, 0.f, 0.f};

    for (int kc = 0; kc < 8; ++kc) {
        const int ci0 = kc << 5;
        __syncthreads();
#pragma unroll
        for (int rnd = 0; rnd < 3; ++rnd) {
            int task = tid + (rnd << 8);
            int row = task >> 2, q = task & 3;
            if (row < NROWS) {
                int dt = row / 85, rem = row - dt * 85;
                int dh = rem / 17, dw = rem - dh * 17;
                int prow = (t + dt) * PT + (h0 + dh) * 17 + dw;
                *(bf16x8*)&sX[row * LROW + (q << 3)] =
                    *(const bf16x8*)(inB + (size_t)prow * 256 + ci0 + (q << 3));
            }
        }
        __syncthreads();
#pragma unroll
        for (int tap = 0; tap < 8; ++tap) {
            const unsigned short* wp = wfrag +
                ((size_t)((((tap << 3) + kc) << 4) + mt0) << 9) + (lane << 3);
            bf16x8 a0 = *(const bf16x8*)(wp);
            bf16x8 a1 = *(const bf16x8*)(wp + 512);
            bf16x8 a2 = *(const bf16x8*)(wp + 1024);
            bf16x8 a3 = *(const bf16x8*)(wp + 1536);
            const int rb = (tap >> 2) * 85 + (wv + ((tap >> 1) & 1)) * 17 + (tap & 1);
            bf16x8 xb = *(const bf16x8*)&sX[(rb + lr) * LROW + (lg << 3)];
            acc[0] = __builtin_amdgcn_mfma_f32_16x16x32_bf16(a0, xb, acc[0], 0, 0, 0);
            acc[1] = __builtin_amdgcn_mfma_f32_16x16x32_bf16(a1, xb, acc[1], 0, 0, 0);
            acc[2] = __builtin_amdgcn_mfma_f32_16x16x32_bf16(a2, xb, acc[2], 0, 0, 0);
            acc[3] = __builtin_amdgcn_mfma_f32_16x16x32_bf16(a3, xb, acc[3], 0, 0, 0);
        }
    }
    const size_t orow = (size_t)b * PROWS + (t + 1) * PT + (h0 + wv + 1) * 17 + (lr + 1);
#pragma unroll
    for (int mi = 0; mi < 4; ++mi) {
        const int cob = ((mt0 + mi) << 4) + (lg << 2);
        unsigned short v4[4];
#pragma unroll
        for (int r = 0; r < 4; ++r)
            v4[r] = f2b(elu_f(acc[mi][r] + bias[cob + r]));
        *(ushort4*)&outP[orow * 256 + cob] = *(ushort4*)v4;
    }
}

// ===== conv2: LDS-staged tap-GEMM + gate =====
__global__ __launch_bounds__(256) void conv2_mfma(
    const unsigned short* __restrict__ inP,
    const unsigned short* __restrict__ wfrag,
    const float* __restrict__ bias,
    float* __restrict__ resf,
    unsigned short* __restrict__ elub)
{
    __shared__ unsigned short sX[NROWS * LROW];

    const int bx = blockIdx.x;
    const int b = bx >> 6, ptile = bx & 63;
    const int t = ptile >> 2, h0 = (ptile & 3) << 2;
    const int mt0 = blockIdx.y << 2;
    const int tid = threadIdx.x;
    const int lane = tid & 63, wv = tid >> 6;
    const int lr = lane & 15, lg = lane >> 4;

    const unsigned short* inB = inP + (size_t)b * PROWS * 256;

    f32x4 acc[4];
#pragma unroll
    for (int mi = 0; mi < 4; ++mi) acc[mi] = (f32x4){0.f, 0.f, 0.f, 0.f};

    for (int kc = 0; kc < 8; ++kc) {
        const int ci0 = kc << 5;
        __syncthreads();
#pragma unroll
        for (int rnd = 0; rnd < 3; ++rnd) {
            int task = tid + (rnd << 8);
            int row = task >> 2, q = task & 3;
            if (row < NROWS) {
                int dt = row / 85, rem = row - dt * 85;
                int dh = rem / 17, dw = rem - dh * 17;
                int prow = (t + dt) * PT + (h0 + dh) * 17 + dw;
                *(bf16x8*)&sX[row * LROW + (q << 3)] =
                    *(const bf16x8*)(inB + (size_t)prow * 256 + ci0 + (q << 3));
            }
        }
        __syncthreads();
#pragma unroll
        for (int tap = 0; tap < 8; ++tap) {
            const unsigned short* wp = wfrag +
                ((size_t)((((tap << 3) + kc) << 5) + mt0) << 9) + (lane << 3);
            bf16x8 a0 = *(const bf16x8*)(wp);
            bf16x8 a1 = *(const bf16x8*)(wp + 512);
            bf16x8 a2 = *(const bf16x8*)(wp + 1024);
            bf16x8 a3 = *(const bf16x8*)(wp + 1536);
            const int rb = (tap >> 2) * 85 + (wv + ((tap >> 1) & 1)) * 17 + (tap & 1);
            bf16x8 xb = *(const bf16x8*)&sX[(rb + lr) * LROW + (lg << 3)];
            acc[0] = __builtin_amdgcn_mfma_f32_16x16x32_bf16(a0, xb, acc[0], 0, 0, 0);
            acc[1] = __builtin_amdgcn_mfma_f32_16x16x32_bf16(a1, xb, acc[1], 0, 0, 0);
            acc[2] = __builtin_amdgcn_mfma_f32_16x16x32_bf16(a2, xb, acc[2], 0, 0, 0);
            acc[3] = __builtin_amdgcn_mfma_f32_16x16x32_bf16(a3, xb, acc[3], 0, 0, 0);
        }
    }
    const int s = (t << 8) + ((h0 + wv) << 4) + lr;
    const size_t prow = (size_t)b * PROWS + (t + 1) * PT + (h0 + wv + 1) * 17 + (lr + 1);
#pragma unroll
    for (int p = 0; p < 2; ++p) {
        const int chb = (((mt0 >> 1) + p) << 4) + (lg << 2);
        unsigned short e4[4];
#pragma unroll
        for (int r = 0; r < 4; ++r) {
            const int ch = chb + r;
            float av = acc[2 * p][r] + bias[ch];
            float gv = acc[2 * p + 1][r] + bias[ch + 256];
            float add = av / (1.0f + expf(-gv));
            size_t ridx = (((size_t)(b * 256 + ch)) << 12) + s;
            float rn = resf[ridx] + add;
            resf[ridx] = rn;
            e4[r] = f2b(elu_f(rn));
        }
        *(ushort4*)&elub[prow * 256 + chb] = *(ushort4*)e4;
    }
}

// ===== pack: xq[b][s][320] = bf16(res | orig | pos | 0) =====
__global__ __launch_bounds__(256) void pack_kernel(
    const float* __restrict__ res, const float* __restrict__ orig,
    unsigned short* __restrict__ xq)
{
    const int b = blockIdx.x >> 5;
    const int s0 = (blockIdx.x & 31) << 7;
    const int cg = blockIdx.y;
    const int tid = threadIdx.x;
    const int s = s0 + (tid & 127);
    const int c0 = cg * 32 + (tid >> 7) * 16;

    unsigned short xv[16];
    if (cg < 8) {
#pragma unroll
        for (int cc = 0; cc < 16; ++cc) {
            int c = c0 + cc;
            float v = res[(size_t)((b * 256 + c) << 12) + s];
            xv[cc] = f2b(v);
        }
    } else if (cg == 8) {
#pragma unroll
        for (int cc = 0; cc < 16; ++cc) {
            int c = c0 + cc;
            float v;
            if (c < 259)      v = orig[(size_t)((b * 3 + (c - 256)) << 12) + s];
            else if (c == 259) v = -0.5f + (float)(s >> 8) * 0.0625f;
            else if (c == 260) v = -0.5f + (float)((s >> 4) & 15) * 0.0625f;
            else if (c == 261) v = -0.5f + (float)(s & 15) * 0.0625f;
            else               v = 0.0f;
            xv[cc] = f2b(v);
        }
    } else {
#pragma unroll
        for (int cc = 0; cc < 16; ++cc) xv[cc] = 0;
    }
    unsigned short* xp = &xq[((size_t)(b << 12) + s) * 320 + c0];
    *(ushort4*)(xp)      = *(ushort4*)&xv[0];
    *(ushort4*)(xp + 4)  = *(ushort4*)&xv[4];
    *(ushort4*)(xp + 8)  = *(ushort4*)&xv[8];
    *(ushort4*)(xp + 12) = *(ushort4*)&xv[12];
}

// ===== wcvt2: all linear weights -> bf16 in MFMA fragment order =====
__global__ __launch_bounds__(256) void wcvt2_kernel(
    const float* __restrict__ qw, const float* __restrict__ kw,
    const float* __restrict__ vw, const float* __restrict__ aw,
    const float* __restrict__ rw, const float* __restrict__ ow,
    unsigned short* __restrict__ wqkv, unsigned short* __restrict__ awb,
    unsigned short* __restrict__ rwb, unsigned short* __restrict__ owb)
{
    int idx = blockIdx.x * 256 + threadIdx.x;
    if (idx < 61440) {
        int frag = idx >> 9, l = (idx >> 3) & 63, e = idx & 7;
        int kc = frag / 12, mt = frag - kc * 12;
        int r = mt * 16 + (l & 15);
        int c = kc * 32 + ((l >> 4) << 3) + e;
        float v = 0.0f;
        if (c < 262) {
            if (r < 16)       v = qw[r * 262 + c];
            else if (r < 32)  v = kw[(r - 16) * 262 + c];
            else if (r < 160) v = vw[(r - 32) * 262 + c];
        }
        wqkv[idx] = f2b(v);
    } else if (idx < 94208) {
        int j = idx - 61440;
        int frag = j >> 9, l = (j >> 3) & 63, e = j & 7;
        int kc = frag >> 4, mt = frag & 15;
        int r = mt * 16 + (l & 15);
        int c = kc * 32 + ((l >> 4) << 3) + e;
        awb[j] = f2b(aw[r * 128 + c]);
    } else if (idx < 159744) {
        int j = idx - 94208;
        int frag = j >> 9, l = (j >> 3) & 63, e = j & 7;
        int kc = frag >> 4, mt = frag & 15;
        int r = mt * 16 + (l & 15);
        int c = kc * 32 + ((l >> 4) << 3) + e;
        rwb[j] = f2b(rw[r * 256 + c]);
    } else if (idx < 225280) {
        int j = idx - 159744;
        int frag = j >> 9, l = (j >> 3) & 63, e = j & 7;
        int kc = frag >> 4, mt = frag & 15;
        int r = mt * 16 + (l & 15);
        int c = kc * 32 + ((l >> 4) << 3) + e;
        owb[j] = f2b(ow[r * 256 + c]);
    }
}

// ===== qkv GEMM (LDS-staged X, fragment W) =====
__global__ __launch_bounds__(256) void qkv_gemm(
    const unsigned short* __restrict__ Wf, const unsigned short* __restrict__ Xt,
    const float* __restrict__ qb, const float* __restrict__ kb,
    const float* __restrict__ vb,
    unsigned short* __restrict__ qbt, unsigned short* __restrict__ kbt,
    unsigned short* __restrict__ vbt)
{
    __shared__ unsigned short sX[128 * GROW];

    const int b = blockIdx.x >> 5;
    const int s0 = (blockIdx.x & 31) << 7;
    const int mt0 = blockIdx.y << 2;
    const int tid = threadIdx.x;
    const int lane = tid & 63, wv = tid >> 6;
    const int lr = lane & 15, lg = lane >> 4;

    f32x4 acc[4][2];
#pragma unroll
    for (int mi = 0; mi < 4; ++mi)
#pragma unroll
        for (int ni = 0; ni < 2; ++ni) acc[mi][ni] = (f32x4){0.f, 0.f, 0.f, 0.f};

    for (int kc = 0; kc < 10; ++kc) {
        __syncthreads();
#pragma unroll
        for (int rnd = 0; rnd < 2; ++rnd) {
            int task = tid + (rnd << 8);
            int row = task >> 2, q = task & 3;
            *(bf16x8*)&sX[row * GROW + (q << 3)] =
                *(const bf16x8*)(Xt + ((size_t)(b << 12) + s0 + row) * 320
                                 + kc * 32 + (q << 3));
        }
        __syncthreads();
        const unsigned short* wp = Wf + ((size_t)(kc * 12 + mt0) << 9) + (lane << 3);
        bf16x8 a0 = *(const bf16x8*)(wp);
        bf16x8 a1 = *(const bf16x8*)(wp + 512);
        bf16x8 a2 = *(const bf16x8*)(wp + 1024);
        bf16x8 a3 = *(const bf16x8*)(wp + 1536);
        bf16x8 x0 = *(const bf16x8*)&sX[(wv * 32 + lr) * GROW + (lg << 3)];
        bf16x8 x1 = *(const bf16x8*)&sX[(wv * 32 + 16 + lr) * GROW + (lg << 3)];
        acc[0][0] = __builtin_amdgcn_mfma_f32_16x16x32_bf16(a0, x0, acc[0][0], 0, 0, 0);
        acc[0][1] = __builtin_amdgcn_mfma_f32_16x16x32_bf16(a0, x1, acc[0][1], 0, 0, 0);
        acc[1][0] = __builtin_amdgcn_mfma_f32_16x16x32_bf16(a1, x0, acc[1][0], 0, 0, 0);
        acc[1][1] = __builtin_amdgcn_mfma_f32_16x16x32_bf16(a1, x1, acc[1][1], 0, 0, 0);
        acc[2][0] = __builtin_amdgcn_mfma_f32_16x16x32_bf16(a2, x0, acc[2][0], 0, 0, 0);
        acc[2][1] = __builtin_amdgcn_mfma_f32_16x16x32_bf16(a2, x1, acc[2][1], 0, 0, 0);
        acc[3][0] = __builtin_amdgcn_mfma_f32_16x16x32_bf16(a3, x0, acc[3][0], 0, 0, 0);
        acc[3][1] = __builtin_amdgcn_mfma_f32_16x16x32_bf16(a3, x1, acc[3][1], 0, 0, 0);
    }
    const int co0 = mt0 << 4;
#pragma unroll
    for (int mi = 0; mi < 4; ++mi)
#pragma unroll
    for (int ni = 0; ni < 2; ++ni)
#pragma unroll
    for (int r = 0; r < 4; ++r) {
        int co = co0 + mi * 16 + lg * 4 + r;
        if (co >= 160) continue;
        int s = s0 + wv * 32 + ni * 16 + lr;
        float bias = (co < 16) ? qb[co] : ((co < 32) ? kb[co - 16] : vb[co - 32]);
        float v = acc[mi][ni][r] + bias;
        if (co < 16)      qbt[((size_t)(b << 12) + s) * 16 + co] = f2b(v);
        else if (co < 32) kbt[((size_t)(b << 12) + s) * 16 + (co - 16)] = f2b(v);
        else              vbt[((size_t)((b << 7) + (co - 32)) << 12) + s] = f2b(v);
    }
}

// ===== attention partial (round-10 form) =====
__global__ __launch_bounds__(256) void attn_part2(
    const unsigned short* __restrict__ qbt, const unsigned short* __restrict__ kbt,
    const unsigned short* __restrict__ vbt,
    float* __restrict__ pacc, float* __restrict__ pml)
{
    const int bx = blockIdx.x;
    const int b = bx >> 8;
    const int qt = (bx >> 2) & 63;
    const int seg = bx & 3;
    const int q0 = qt << 6;
    const int nch = (qt >> 1) + 1;
    const int c_lo = seg << 3;
    if (c_lo >= nch) return;
    const int c_hi = min(c_lo + 8, nch);

    __shared__ unsigned short sK[128 * 16];
    __shared__ unsigned short sP[4][16 * 136];

    const int tid = threadIdx.x;
    const int lane = tid & 63, wv = tid >> 6;
    const int lr = lane & 15, lg = lane >> 4;
    const int qa = q0 + wv * 16 + lr;
    const float scale = 1.0f / sqrtf(259.0f);

    bf16x8 qf = (bf16x8){0, 0, 0, 0, 0, 0, 0, 0};
    if (lg < 2)
        qf = *(const bf16x8*)(qbt + ((size_t)(b << 12) + qa) * 16 + lg * 8);

    f32x4 oacc[8];
#pragma unroll
    for (int vct = 0; vct < 8; ++vct) oacc[vct] = (f32x4){0.f, 0.f, 0.f, 0.f};
    float m = -1e30f, l = 0.0f;

    unsigned short* myP = &sP[wv][0];

    for (int kc = c_lo; kc < c_hi; ++kc) {
        const int kv0 = kc << 7;
        __syncthreads();
        *(bf16x8*)&sK[(tid >> 1) * 16 + (tid & 1) * 8] =
            *(const bf16x8*)(kbt + ((size_t)(b << 12) + kv0 + (tid >> 1)) * 16 + (tid & 1) * 8);
        __syncthreads();

        f32x4 sc[8];
#pragma unroll
        for (int kvt = 0; kvt < 8; ++kvt) {
            bf16x8 af = (bf16x8){0, 0, 0, 0, 0, 0, 0, 0};
            if (lg < 2)
                af = *(const bf16x8*)&sK[(kvt * 16 + lr) * 16 + lg * 8];
            sc[kvt] = __builtin_amdgcn_mfma_f32_16x16x32_bf16(
                af, qf, (f32x4){0.f, 0.f, 0.f, 0.f}, 0, 0, 0);
        }
        float mc = -1e30f;
#pragma unroll
        for (int kvt = 0; kvt < 8; ++kvt) {
#pragma unroll
            for (int r = 0; r < 4; ++r) {
                int kv = kv0 + kvt * 16 + lg * 4 + r;
                float s = (kv < qa) ? sc[kvt][r] * scale : -1e30f;
                sc[kvt][r] = s;
                mc = fmaxf(mc, s);
            }
        }
        mc = fmaxf(mc, __shfl_xor(mc, 16, 64));
        mc = fmaxf(mc, __shfl_xor(mc, 32, 64));
        float mn = fmaxf(m, mc);
        float fac = __expf(m - mn);
        float ls = 0.0f;
#pragma unroll
        for (int kvt = 0; kvt < 8; ++kvt) {
#pragma unroll
            for (int e = 0; e < 2; ++e) {
                float s0v = sc[kvt][2 * e];
                float s1v = sc[kvt][2 * e + 1];
                float p0 = (s0v <= -1e29f) ? 0.f : __expf(s0v - mn);
                float p1 = (s1v <= -1e29f) ? 0.f : __expf(s1v - mn);
                ls += p0 + p1;
                unsigned int pk = (unsigned int)f2b(p0) | ((unsigned int)f2b(p1) << 16);
                int kv = kvt * 16 + lg * 4 + 2 * e;
                *(unsigned int*)&myP[lr * 136 + kv] = pk;
            }
        }
        ls += __shfl_xor(ls, 16, 64);
        ls += __shfl_xor(ls, 32, 64);
        l = l * fac + ls;
        m = mn;
#pragma unroll
        for (int vct = 0; vct < 8; ++vct) {
            oacc[vct][0] *= fac; oacc[vct][1] *= fac;
            oacc[vct][2] *= fac; oacc[vct][3] *= fac;
        }
#pragma unroll
        for (int ks = 0; ks < 4; ++ks) {
            bf16x8 pf = *(const bf16x8*)&myP[lr * 136 + ks * 32 + lg * 8];
#pragma unroll
            for (int vct = 0; vct < 8; ++vct) {
                bf16x8 vf = *(const bf16x8*)(vbt +
                    ((size_t)((b << 7) + vct * 16 + lr) << 12) + kv0 + ks * 32 + lg * 8);
                oacc[vct] = __builtin_amdgcn_mfma_f32_16x16x32_bf16(
                    vf, pf, oacc[vct], 0, 0, 0);
            }
        }
    }

    const int a_ = qt >> 4;
    const int slot = b * 160 + 8 * a_ * (a_ + 1) + (qt & 15) * (a_ + 1) + seg;
    float* ap = pacc + (size_t)slot * 8192;
#pragma unroll
    for (int vct = 0; vct < 8; ++vct)
        *(f32x4*)&ap[(wv * 16 + lr) * 128 + vct * 16 + lg * 4] = oacc[vct];
    if (lg == 0) {
        pml[slot * 128 + (wv * 16 + lr) * 2]     = m;
        pml[slot * 128 + (wv * 16 + lr) * 2 + 1] = l;
    }
}

// ===== attention combine =====
__global__ __launch_bounds__(256) void attn_combine2(
    const float* __restrict__ pacc, const float* __restrict__ pml,
    unsigned short* __restrict__ attEb)
{
    const int bx = blockIdx.x;
    const int b = bx >> 7;
    const int qt = (bx >> 1) & 63;
    const int half = bx & 1;
    const int a_ = qt >> 4;
    const int nseg_alloc = a_ + 1;
    const int nch = (qt >> 1) + 1;
    const int nseg = (nch + 7) >> 3;
    const int base = b * 160 + 8 * a_ * (a_ + 1) + (qt & 15) * nseg_alloc;
    const int tid = threadIdx.x;
    const int qq = (tid >> 3) + half * 32;
    const int vg = tid & 7;

    float mi_[4], li_[4];
    float m = -1e30f;
    for (int i = 0; i < nseg; ++i) {
        mi_[i] = pml[(base + i) * 128 + qq * 2];
        li_[i] = pml[(base + i) * 128 + qq * 2 + 1];
        m = fmaxf(m, mi_[i]);
    }
    float w[4];
    float l = 0.f;
    for (int i = 0; i < nseg; ++i) {
        float wi = (mi_[i] <= -1e29f) ? 0.f : __expf(mi_[i] - m);
        w[i] = wi;
        l += wi * li_[i];
    }
    float inv = (l > 0.f) ? 1.f / l : 0.f;
    int q = (qt << 6) + qq;
#pragma unroll
    for (int v4 = 0; v4 < 4; ++v4) {
        int vc = vg * 16 + v4 * 4;
        float o0 = 0.f, o1 = 0.f, o2 = 0.f, o3 = 0.f;
        for (int i = 0; i < nseg; ++i) {
            f32x4 a = *(const f32x4*)(pacc + (size_t)(base + i) * 8192 + qq * 128 + vc);
            o0 = fmaf(w[i], a[0], o0);
            o1 = fmaf(w[i], a[1], o1);
            o2 = fmaf(w[i], a[2], o2);
            o3 = fmaf(w[i], a[3], o3);
        }
        unsigned short r0 = f2b(elu_f(o0 * inv));
        unsigned short r1 = f2b(elu_f(o1 * inv));
        unsigned short r2 = f2b(elu_f(o2 * inv));
        unsigned short r3 = f2b(elu_f(o3 * inv));
        ushort4 pk = {r0, r1, r2, r3};
        *(ushort4*)&attEb[((size_t)(b << 12) + q) * 128 + vc] = pk;
    }
}

// ===== final_ab GEMM (LDS-staged) =====
__global__ __launch_bounds__(256) void final_ab_gemm(
    const unsigned short* __restrict__ W1f, const unsigned short* __restrict__ W2f,
    const unsigned short* __restrict__ X1, const unsigned short* __restrict__ X2,
    const float* __restrict__ b1, const float* __restrict__ b2,
    unsigned short* __restrict__ sum2b)
{
    __shared__ unsigned short sX[128 * GROW];

    const int b = blockIdx.x >> 5;
    const int s0 = (blockIdx.x & 31) << 7;
    const int mt0 = blockIdx.y << 2;
    const int tid = threadIdx.x;
    const int lane = tid & 63, wv = tid >> 6;
    const int lr = lane & 15, lg = lane >> 4;

    f32x4 acc1[4][2], acc2[4][2];
#pragma unroll
    for (int mi = 0; mi < 4; ++mi)
#pragma unroll
        for (int ni = 0; ni < 2; ++ni) {
            acc1[mi][ni] = (f32x4){0.f, 0.f, 0.f, 0.f};
            acc2[mi][ni] = (f32x4){0.f, 0.f, 0.f, 0.f};
        }

    for (int kc = 0; kc < 4; ++kc) {
        __syncthreads();
#pragma unroll
        for (int rnd = 0; rnd < 2; ++rnd) {
            int task = tid + (rnd << 8);
            int row = task >> 2, q = task & 3;
            *(bf16x8*)&sX[row * GROW + (q << 3)] =
                *(const bf16x8*)(X1 + ((size_t)(b << 12) + s0 + row) * 128
                                 + kc * 32 + (q << 3));
        }
        __syncthreads();
        const unsigned short* wp = W1f + ((size_t)((kc << 4) + mt0) << 9) + (lane << 3);
        bf16x8 a0 = *(const bf16x8*)(wp);
        bf16x8 a1 = *(const bf16x8*)(wp + 512);
        bf16x8 a2 = *(const bf16x8*)(wp + 1024);
        bf16x8 a3 = *(const bf16x8*)(wp + 1536);
        bf16x8 x0 = *(const bf16x8*)&sX[(wv * 32 + lr) * GROW + (lg << 3)];
        bf16x8 x1 = *(const bf16x8*)&sX[(wv * 32 + 16 + lr) * GROW + (lg << 3)];
        acc1[0][0] = __builtin_amdgcn_mfma_f32_16x16x32_bf16(a0, x0, acc1[0][0], 0, 0, 0);
        acc1[0][1] = __builtin_amdgcn_mfma_f32_16x16x32_bf16(a0, x1, acc1[0][1], 0, 0, 0);
        acc1[1][0] = __builtin_amdgcn_mfma_f32_16x16x32_bf16(a1, x0, acc1[1][0], 0, 0, 0);
        acc1[1][1] = __builtin_amdgcn_mfma_f32_16x16x32_bf16(a1, x1, acc1[1][1], 0, 0, 0);
        acc1[2][0] = __builtin_amdgcn_mfma_f32_16x16x32_bf16(a2, x0, acc1[2][0], 0, 0, 0);
        acc1[2][1] = __builtin_amdgcn_mfma_f32_16x16x32_bf16(a2, x1, acc1[2][1], 0, 0, 0);
        acc1[3][0] = __builtin_amdgcn_mfma_f32_16x16x32_bf16(a3, x0, acc1[3][0], 0, 0, 0);
        acc1[3][1] = __builtin_amdgcn_mfma_f32_16x16x32_bf16(a3, x1, acc1[3][1], 0, 0, 0);
    }
    for (int kc = 0; kc < 8; ++kc) {
        __syncthreads();
#pragma unroll
        for (int rnd = 0; rnd < 2; ++rnd) {
            int task = tid + (rnd << 8);
            int row = task >> 2, q = task & 3;
            int s = s0 + row;
            int tt = s >> 8, hh = (s >> 4) & 15, ww = s & 15;
            size_t prow = (size_t)b * PROWS + (tt + 1) * PT + (hh + 1) * 17 + (ww + 1);
            *(bf16x8*)&sX[row * GROW + (q << 3)] =
                *(const bf16x8*)(X2 + prow * 256 + kc * 32 + (q << 3));
        }
        __syncthreads();
        const unsigned short* wp = W2f + ((size_t)((kc << 4) + mt0) << 9) + (lane << 3);
        bf16x8 a0 = *(const bf16x8*)(wp);
        bf16x8 a1 = *(const bf16x8*)(wp + 512);
        bf16x8 a2 = *(const bf16x8*)(wp + 1024);
        bf16x8 a3 = *(const bf16x8*)(wp + 1536);
        bf16x8 x0 = *(const bf16x8*)&sX[(wv * 32 + lr) * GROW + (lg << 3)];
        bf16x8 x1 = *(const bf16x8*)&sX[(wv * 32 + 16 + lr) * GROW + (lg << 3)];
        acc2[0][0] = __builtin_amdgcn_mfma_f32_16x16x32_bf16(a0, x0, acc2[0][0], 0, 0, 0);
        acc2[0][1] = __builtin_amdgcn_mfma_f32_16x16x32_bf16(a0, x1, acc2[0][1], 0, 0, 0);
        acc2[1][0] = __builtin_amdgcn_mfma_f32_16x16x32_bf16(a1, x0, acc2[1][0], 0, 0, 0);
        acc2[1][1] = __builtin_amdgcn_mfma_f32_16x16x32_bf16(a1, x1, acc2[1][1], 0, 0, 0);
        acc2[2][0] = __builtin_amdgcn_mfma_f32_16x16x32_bf16(a2, x0, acc2[2][0], 0, 0, 0);
        acc2[2][1] = __builtin_amdgcn_mfma_f32_16x16x32_bf16(a2, x1, acc2[2][1], 0, 0, 0);
        acc2[3][0] = __builtin_amdgcn_mfma_f32_16x16x32_bf16(a3, x0, acc2[3][0], 0, 0, 0);
        acc2[3][1] = __builtin_amdgcn_mfma_f32_16x16x32_bf16(a3, x1, acc2[3][1], 0, 0, 0);
    }
    const int co0 = mt0 << 4;
#pragma unroll
    for (int mi = 0; mi < 4; ++mi)
#pragma unroll
    for (int ni = 0; ni < 2; ++ni)
#pragma unroll
    for (int r = 0; r < 4; ++r) {
        int co = co0 + mi * 16 + lg * 4 + r;
        int s = s0 + wv * 32 + ni * 16 + lr;
        float v1 = elu_f(acc1[mi][ni][r] + b1[co]);
        float v2 = elu_f(acc2[mi][ni][r] + b2[co]);
        sum2b[((size_t)(b << 12) + s) * 256 + co] = f2b(elu_f(v1 + v2));
    }
}

// ===== final_c GEMM (LDS-staged) =====
__global__ __launch_bounds__(256) void final_c_gemm(
    const unsigned short* __restrict__ Wf, const unsigned short* __restrict__ Xt,
    const float* __restrict__ bias, float* __restrict__ out)
{
    __shared__ unsigned short sX[128 * GROW];

    const int b = blockIdx.x >> 5;
    const int s0 = (blockIdx.x & 31) << 7;
    const int mt0 = blockIdx.y << 2;
    const int tid = threadIdx.x;
    const int lane = tid & 63, wv = tid >> 6;
    const int lr = lane & 15, lg = lane >> 4;

    f32x4 acc[4][2];
#pragma unroll
    for (int mi = 0; mi < 4; ++mi)
#pragma unroll
        for (int ni = 0; ni < 2; ++ni) acc[mi][ni] = (f32x4){0.f, 0.f, 0.f, 0.f};

    for (int kc = 0; kc < 8; ++kc) {
        __syncthreads();
#pragma unroll
        for (int rnd = 0; rnd < 2; ++rnd) {
            int task = tid + (rnd << 8);
            int row = task >> 2, q = task & 3;
            *(bf16x8*)&sX[row * GROW + (q << 3)] =
                *(const bf16x8*)(Xt + ((size_t)(b << 12) + s0 + row) * 256
                                 + kc * 32 + (q << 3));
        }
        __syncthreads();
        const unsigned short* wp = Wf + ((size_t)((kc << 4) + mt0) << 9) + (lane << 3);
        bf16x8 a0 = *(const bf16x8*)(wp);
        bf16x8 a1 = *(const bf16x8*)(wp + 512);
        bf16x8 a2 = *(const bf16x8*)(wp + 1024);
        bf16x8 a3 = *(const bf16x8*)(wp + 1536);
        bf16x8 x0 = *(const bf16x8*)&sX[(wv * 32 + lr) * GROW + (lg << 3)];
        bf16x8 x1 = *(const bf16x8*)&sX[(wv * 32 + 16 + lr) * GROW + (lg << 3)];
        acc[0][0] = __builtin_amdgcn_mfma_f32_16x16x32_bf16(a0, x0, acc[0][0], 0, 0, 0);
        acc[0][1] = __builtin_amdgcn_mfma_f32_16x16x32_bf16(a0, x1, acc[0][1], 0, 0, 0);
        acc[1][0] = __builtin_amdgcn_mfma_f32_16x16x32_bf16(a1, x0, acc[1][0], 0, 0, 0);
        acc[1][1] = __builtin_amdgcn_mfma_f32_16x16x32_bf16(a1, x1, acc[1][1], 0, 0, 0);
        acc[2][0] = __builtin_amdgcn_mfma_f32_16x16x32_bf16(a2, x0, acc[2][0], 0, 0, 0);
        acc[2][1] = __builtin_amdgcn_mfma_f32_16x16x32_bf16(a2, x1, acc[2][1], 0, 0, 0);
        acc[3][0] = __builtin_amdgcn_mfma_f32_16x16x32_bf16(a3, x0, acc[3][0], 0, 0, 0);
        acc[3][1] = __builtin_amdgcn_mfma_f32_16x16x32_bf16(a3, x1, acc[3][1], 0, 0, 0);
    }
    const int co0 = mt0 << 4;
#pragma unroll
    for (int mi = 0; mi < 4; ++mi)
#pragma unroll
    for (int ni = 0; ni < 2; ++ni)
#pragma unroll
    for (int r = 0; r < 4; ++r) {
        int co = co0 + mi * 16 + lg * 4 + r;
        int s = s0 + wv * 32 + ni * 16 + lr;
        out[((size_t)(b * 256 + co) << 12) + s] = elu_f(acc[mi][ni][r] + bias[co]);
    }
}

extern "C" void kernel_launch(void* const* d_in, const int* in_sizes, int n_in,
                              void* d_out, int out_size, void* d_ws, size_t ws_size,
                              hipStream_t stream) {
    const float* x      = (const float*)d_in[0];
    const float* orig   = (const float*)d_in[1];
    const float* rb_w1  = (const float*)d_in[2];
    const float* rb_b1  = (const float*)d_in[3];
    const float* rb_w2  = (const float*)d_in[4];
    const float* rb_b2  = (const float*)d_in[5];
    const float* q_w    = (const float*)d_in[6];
    const float* q_b    = (const float*)d_in[7];
    const float* k_w    = (const float*)d_in[8];
    const float* k_b    = (const float*)d_in[9];
    const float* v_w    = (const float*)d_in[10];
    const float* v_b    = (const float*)d_in[11];
    const float* attn_w = (const float*)d_in[12];
    const float* attn_b = (const float*)d_in[13];
    const float* resc_w = (const float*)d_in[14];
    const float* resc_b = (const float*)d_in[15];
    const float* out_w  = (const float*)d_in[16];
    const float* out_b  = (const float*)d_in[17];
    float* out = (float*)d_out;

    char* base = (char*)d_ws;
    float*          res   = (float*)(base);                          // 0..8MB
    unsigned short* elubP = (unsigned short*)(base + (8u << 20));    // 8..13MB padded
    unsigned short* o1P   = (unsigned short*)(base + (13u << 20));   // 13..18MB padded
    unsigned short* w1t   = (unsigned short*)(base + (18u << 20));   // 18..22MB
    unsigned short* w2t   = (unsigned short*)(base + (22u << 20));   // 22..30MB
    unsigned short* vbt   = o1P;                                     // 2MB @13MB
    unsigned short* attEb = (unsigned short*)(base + (15u << 20));   // 2MB @15MB
    unsigned short* sum2b = w1t;
    unsigned short* xqkvB = w2t;                                     // 5MB @22MB
    float*          pacc  = (float*)(base + (22u << 20));            // 10MB @22MB
    unsigned short* qbt   = (unsigned short*)(base + (32u << 20));
    unsigned short* kbt   = (unsigned short*)(base + (32u << 20) + 262144);
    unsigned short* wqkvB = (unsigned short*)(base + (32u << 20) + 524288);
    unsigned short* attnWb= (unsigned short*)(base + (32u << 20) + 655360);
    unsigned short* rescWb= (unsigned short*)(base + (32u << 20) + 720896);
    unsigned short* outWb = (unsigned short*)(base + (32u << 20) + 851968);
    float*          pml   = (float*)(base + (32u << 20) + 983040);

    const int nz = (2 * PROWS * 256 * 2) / 16;
    zero2_kernel<<<(nz + 255) / 256, 256, 0, stream>>>(
        (uint4*)elubP, (uint4*)o1P, nz);

    hipMemcpyAsync(res, x, (size_t)2097152 * sizeof(float),
                   hipMemcpyDeviceToDevice, stream);
    prep_t<<<dim3(64, 8), 256, 0, stream>>>(x, elubP);
    wcvt_kernel<<<16384, 256, 0, stream>>>(rb_w1, rb_w2, w1t, w2t);

    for (int i = 0; i < 4; ++i) {
        conv1_mfma<<<dim3(128, 4), 256, 0, stream>>>(
            elubP, w1t + (size_t)i * 524288, rb_b1 + i * 256, o1P);
        conv2_mfma<<<dim3(128, 8), 256, 0, stream>>>(
            o1P, w2t + (size_t)i * 1048576, rb_b2 + i * 512, res, elubP);
    }

    pack_kernel<<<dim3(64, 10), 256, 0, stream>>>(res, orig, xqkvB);
    wcvt2_kernel<<<880, 256, 0, stream>>>(q_w, k_w, v_w, attn_w, resc_w, out_w,
                                          wqkvB, attnWb, rescWb, outWb);

    qkv_gemm<<<dim3(64, 3), 256, 0, stream>>>(wqkvB, xqkvB, q_b, k_b, v_b,
                                              qbt, kbt, vbt);

    attn_part2<<<512, 256, 0, stream>>>(qbt, kbt, vbt, pacc, pml);
    attn_combine2<<<256, 256, 0, stream>>>(pacc, pml, attEb);

    final_ab_gemm<<<dim3(64, 4), 256, 0, stream>>>(
        attnWb, rescWb, attEb, elubP, attn_b, resc_b, sum2b);

    final_c_gemm<<<dim3(64, 4), 256, 0, stream>>>(outWb, sum2b, out_b, out);
}